// Round 10
// baseline (113.224 us; speedup 1.0000x reference)
//
#include <hip/hip_runtime.h>
#include <stdint.h>

#define T_SEQ 2048
#define CIN 256
#define COUT 512
#define NHEAD 8
#define DH 64
#define LROW 72  // LDS row stride in elems (144B: 16B-aligned, 9 granules -> even bank spread)

typedef __bf16 bf16x8 __attribute__((ext_vector_type(8)));
typedef float f32x4 __attribute__((ext_vector_type(4)));
typedef float f32x16 __attribute__((ext_vector_type(16)));
typedef unsigned short u16x8 __attribute__((ext_vector_type(8)));
typedef unsigned u32x4 __attribute__((ext_vector_type(4)));

static __device__ __forceinline__ unsigned short bf16_rne(float f) {
  unsigned u = __builtin_bit_cast(unsigned, f);
  u += 0x7FFFu + ((u >> 16) & 1u);
  return (unsigned short)(u >> 16);
}

static __device__ __forceinline__ unsigned cvt_pk_bf16(float lo, float hi) {
  unsigned r;
  asm("v_cvt_pk_bf16_f32 %0, %1, %2" : "=v"(r) : "v"(lo), "v"(hi));
  return r;
}

// in-place cross-half swap (T12)
static __device__ __forceinline__ void plswap(unsigned& a, unsigned& b) {
  auto rr = __builtin_amdgcn_permlane32_swap((int)a, (int)b, false, false);
  a = (unsigned)rr[0];
  b = (unsigned)rr[1];
}

static __device__ __forceinline__ bf16x8 ld_frag(const unsigned short* p) {
  u16x8 v = *(const u16x8*)p;
  return __builtin_bit_cast(bf16x8, v);
}

// ---------------- pack: weights f32 -> bf16 ----------------
__global__ __launch_bounds__(256) void pack_w_k(const float* __restrict__ wq,
                                                const float* __restrict__ wk,
                                                const float* __restrict__ wv,
                                                unsigned short* __restrict__ wb) {
  int i = blockIdx.x * 256 + threadIdx.x;
  const float* src = (i < 131072) ? wq : (i < 262144) ? wk : wv;
  wb[i] = bf16_rne(src[i & 131071]);
}

// ---------------- pack: x (n,c,t) f32 -> xT (n,t,c) bf16 ----------------
__global__ __launch_bounds__(256) void pack_xT_k(const float* __restrict__ x,
                                                 unsigned short* __restrict__ xT) {
  __shared__ float tile[64][65];
  const int n = blockIdx.z, c0 = blockIdx.y * 64, t0 = blockIdx.x * 64;
  const int i = threadIdx.x;
  {
    const int cc = i >> 2, tch = (i & 3) * 16;
    const float* src = x + ((size_t)n * CIN + c0 + cc) * T_SEQ + t0 + tch;
    const float4* s4 = (const float4*)src;
#pragma unroll
    for (int q = 0; q < 4; ++q) {
      float4 v = s4[q];
      tile[cc][tch + q * 4 + 0] = v.x;
      tile[cc][tch + q * 4 + 1] = v.y;
      tile[cc][tch + q * 4 + 2] = v.z;
      tile[cc][tch + q * 4 + 3] = v.w;
    }
  }
  __syncthreads();
  {
    const int tt = i >> 2, cch = (i & 3) * 16;
    unsigned short* dst = xT + ((size_t)n * T_SEQ + t0 + tt) * CIN + c0 + cch;
    u16x8 w0, w1;
#pragma unroll
    for (int j = 0; j < 8; ++j) w0[j] = bf16_rne(tile[cch + j][tt]);
#pragma unroll
    for (int j = 0; j < 8; ++j) w1[j] = bf16_rne(tile[cch + 8 + j][tt]);
    *(u16x8*)dst = w0;
    *(u16x8*)(dst + 8) = w1;
  }
}

// ---------------- projection (V written d-major via LDS transpose) ----------------
__global__ __launch_bounds__(256) void proj_k(const unsigned short* __restrict__ wb,
                                              const unsigned short* __restrict__ xT,
                                              unsigned short* __restrict__ qb,
                                              unsigned short* __restrict__ kb,
                                              unsigned short* __restrict__ vb) {
  __shared__ unsigned short vt_lds[64][136];  // 64 o x 128 t, stride 136 (16B-aligned rows)
  const int z = blockIdx.z;
  const int n = z / 3, w = z % 3;
  const unsigned short* W = wb + (size_t)w * COUT * CIN;
  const unsigned short* X = xT + (size_t)n * T_SEQ * CIN;
  const int tid = threadIdx.x, wave = tid >> 6, lane = tid & 63;
  const int c = lane & 15, g = lane >> 4;
  const int o0 = blockIdx.x * 64;
  const int t0 = blockIdx.y * 128 + wave * 32;

  f32x4 acc[2][4];
  const f32x4 z4 = {0.f, 0.f, 0.f, 0.f};
#pragma unroll
  for (int mt = 0; mt < 2; ++mt)
#pragma unroll
    for (int no = 0; no < 4; ++no) acc[mt][no] = z4;

  for (int c0 = 0; c0 < CIN; c0 += 32) {
    bf16x8 a[2], b[4];
#pragma unroll
    for (int mt = 0; mt < 2; ++mt)
      a[mt] = ld_frag(X + (size_t)(t0 + mt * 16 + c) * CIN + c0 + g * 8);
#pragma unroll
    for (int no = 0; no < 4; ++no)
      b[no] = ld_frag(W + (size_t)(o0 + no * 16 + c) * CIN + c0 + g * 8);
#pragma unroll
    for (int mt = 0; mt < 2; ++mt)
#pragma unroll
      for (int no = 0; no < 4; ++no)
        acc[mt][no] = __builtin_amdgcn_mfma_f32_16x16x32_bf16(a[mt], b[no], acc[mt][no], 0, 0, 0);
  }

  const int h = o0 >> 6;
  const size_t base = ((size_t)(n * NHEAD + h)) * T_SEQ * DH;
  if (w == 2) {
    // stage to LDS d-major, then coalesced global store
#pragma unroll
    for (int mt = 0; mt < 2; ++mt)
#pragma unroll
      for (int no = 0; no < 4; ++no) {
        const int d = no * 16 + c;
        const int lt = (wave * 32) + mt * 16 + 4 * g;
#pragma unroll
        for (int pr = 0; pr < 2; ++pr) {
          const unsigned pw = (unsigned)bf16_rne(acc[mt][no][2 * pr]) |
                              ((unsigned)bf16_rne(acc[mt][no][2 * pr + 1]) << 16);
          *(unsigned*)&vt_lds[d][lt + 2 * pr] = pw;
        }
      }
    __syncthreads();
    const int row = tid >> 2, seg = tid & 3;
    unsigned short* dst = vb + base + (size_t)row * T_SEQ + blockIdx.y * 128 + seg * 32;
    const unsigned short* srcl = &vt_lds[row][seg * 32];
#pragma unroll
    for (int q = 0; q < 4; ++q) *(u16x8*)(dst + q * 8) = *(const u16x8*)(srcl + q * 8);
  } else {
    unsigned short* dst = (w == 0) ? qb : kb;
    // fold 1/sqrt(dk) * log2(e) into q so attention uses exp2 directly
    const float scale = (w == 0) ? 0.18033688011112043f : 1.0f;
#pragma unroll
    for (int mt = 0; mt < 2; ++mt)
#pragma unroll
      for (int no = 0; no < 4; ++no)
#pragma unroll
        for (int r = 0; r < 4; ++r) {
          const int t = t0 + mt * 16 + 4 * g + r;
          const int d = no * 16 + c;
          dst[base + (size_t)t * DH + d] = bf16_rne(acc[mt][no][r] * scale);
        }
  }
}

// ---------------- flash attention: 8 waves, tk-split + PHASE-STAGGERED halves ----------------
// grid 512 (XCD-swizzled -> 16 tq-tiles x 32 nh), block 512 (2 tk-halves x 4 waves x 32 tq).
// In every barrier window one half does QK (MFMA+LDS) while the other does softmax+PV
// (trans/VALU+MFMA) -> pipe overlap instead of lockstep convoy.
// 32x32x16 MFMA; in-register softmax via cvt_pk + permlane32_swap; no max tracking (bounded);
// exact end-merge: O = O_a + O_b, l = l_a + l_b.
__global__ __launch_bounds__(512) void attn_k(const unsigned short* __restrict__ qb,
                                              const unsigned short* __restrict__ kb,
                                              const unsigned short* __restrict__ vbt,
                                              float* __restrict__ outp) {
  __shared__ unsigned short Kl[2][2][64 * LROW];  // [half][dbuf]; rows tk, d contiguous
  __shared__ unsigned short Vt[2][2][64 * LROW];  // [half][dbuf]; rows d, tk contiguous

  // XCD-bijective swizzle: 512 blocks, 8 XCDs -> 64 contiguous sids per XCD
  const int bid = blockIdx.x;
  const int sid = (bid & 7) * 64 + (bid >> 3);
  const int tqt = sid & 15, nh = sid >> 4;

  const int tid = threadIdx.x;
  const int wave = tid >> 6, lane = tid & 63;
  const int half = wave >> 2;  // tk half: 0 -> [0,1024), 1 -> [1024,2048)
  const int ln = lane & 31, hi = lane >> 5;
  const int tq0 = tqt * 128 + (wave & 3) * 32;
  const unsigned short* Q = qb + (size_t)nh * T_SEQ * DH;
  const unsigned short* K = kb + (size_t)nh * T_SEQ * DH;   // [t][d]
  const unsigned short* V = vbt + (size_t)nh * T_SEQ * DH;  // [d][t]

  // Q fragments: B-operand, lane ln = tq col, k = d = dblk*16 + hi*8 + j
  bf16x8 qf[4];
#pragma unroll
  for (int dblk = 0; dblk < 4; ++dblk)
    qf[dblk] = ld_frag(Q + (size_t)(tq0 + ln) * DH + dblk * 16 + hi * 8);

  const f32x16 z16 = {0.f, 0.f, 0.f, 0.f, 0.f, 0.f, 0.f, 0.f,
                      0.f, 0.f, 0.f, 0.f, 0.f, 0.f, 0.f, 0.f};
  f32x16 oacc0 = z16, oacc1 = z16;  // O cols: oacc0 -> d=ln, oacc1 -> d=32+ln
  float l_run = 0.f;

  // ---- staging decomposition within half (256 threads): row = ht&63, seg = ht>>6 ----
  const int ht = tid & 255;
  const int srow = ht & 63, sseg = ht >> 6;
  const unsigned short* kseg = K + (size_t)(half * 1024 + srow) * DH + sseg * 16;  // +64*DH/tile
  const unsigned short* vseg = V + (size_t)srow * T_SEQ + half * 1024 + sseg * 16; // +64/tile
  const int swoff = srow * LROW + sseg * 16;
  // read row offsets (elems)
  const int row0 = ln * LROW;
  const int row1 = (32 + ln) * LROW;
  const int hioff = hi * 8;

  // ---- helpers (wave-local) ----
  auto qk = [&](const unsigned short* kbp, f32x16& s0, f32x16& s1) {
    s0 = z16;
    s1 = z16;
    __builtin_amdgcn_s_setprio(1);
#pragma unroll
    for (int dblk = 0; dblk < 4; ++dblk) {
      bf16x8 ka0 = ld_frag(kbp + row0 + dblk * 16 + hioff);
      bf16x8 ka1 = ld_frag(kbp + row1 + dblk * 16 + hioff);
      s0 = __builtin_amdgcn_mfma_f32_32x32x16_bf16(ka0, qf[dblk], s0, 0, 0, 0);
      s1 = __builtin_amdgcn_mfma_f32_32x32x16_bf16(ka1, qf[dblk], s1, 0, 0, 0);
    }
    __builtin_amdgcn_s_setprio(0);
  };
  auto smpv = [&](const f32x16& s0, const f32x16& s1, const unsigned short* vbp) {
    float p0[16], p1[16];
    float cs = 0.f;
#pragma unroll
    for (int r = 0; r < 16; ++r) {
      p0[r] = __builtin_amdgcn_exp2f(s0[r]);
      p1[r] = __builtin_amdgcn_exp2f(s1[r]);
      cs += p0[r] + p1[r];
    }
    cs += __shfl_xor(cs, 32);
    l_run += cs;
    unsigned W0[8], W1[8];
#pragma unroll
    for (int j = 0; j < 8; ++j) {
      W0[j] = cvt_pk_bf16(p0[2 * j], p0[2 * j + 1]);
      W1[j] = cvt_pk_bf16(p1[2 * j], p1[2 * j + 1]);
    }
    plswap(W0[0], W0[2]);
    plswap(W0[1], W0[3]);
    plswap(W0[4], W0[6]);
    plswap(W0[5], W0[7]);
    plswap(W1[0], W1[2]);
    plswap(W1[1], W1[3]);
    plswap(W1[4], W1[6]);
    plswap(W1[5], W1[7]);
    bf16x8 pa[4];
    {
      u32x4 f;
      f[0] = W0[0]; f[1] = W0[1]; f[2] = W0[2]; f[3] = W0[3];
      pa[0] = __builtin_bit_cast(bf16x8, f);
      f[0] = W0[4]; f[1] = W0[5]; f[2] = W0[6]; f[3] = W0[7];
      pa[1] = __builtin_bit_cast(bf16x8, f);
      f[0] = W1[0]; f[1] = W1[1]; f[2] = W1[2]; f[3] = W1[3];
      pa[2] = __builtin_bit_cast(bf16x8, f);
      f[0] = W1[4]; f[1] = W1[5]; f[2] = W1[6]; f[3] = W1[7];
      pa[3] = __builtin_bit_cast(bf16x8, f);
    }
    __builtin_amdgcn_s_setprio(1);
#pragma unroll
    for (int kbk = 0; kbk < 4; ++kbk) {
      bf16x8 vf0 = ld_frag(vbp + row0 + kbk * 16 + hioff);
      bf16x8 vf1 = ld_frag(vbp + row1 + kbk * 16 + hioff);
      oacc0 = __builtin_amdgcn_mfma_f32_32x32x16_bf16(pa[kbk], vf0, oacc0, 0, 0, 0);
      oacc1 = __builtin_amdgcn_mfma_f32_32x32x16_bf16(pa[kbk], vf1, oacc1, 0, 0, 0);
    }
    __builtin_amdgcn_s_setprio(0);
  };

  // ---- prologue: stage tile 0 of this half ----
  unsigned short* krb = &Kl[half][0][0];
  unsigned short* kab = &Kl[half][1][0];
  unsigned short* vrb = &Vt[half][0][0];
  unsigned short* vab = &Vt[half][1][0];
  {
    u16x8 k0 = *(const u16x8*)kseg;
    u16x8 k1 = *(const u16x8*)(kseg + 8);
    u16x8 v0 = *(const u16x8*)vseg;
    u16x8 v1 = *(const u16x8*)(vseg + 8);
    *(u16x8*)&krb[swoff] = k0;
    *(u16x8*)&krb[swoff + 8] = k1;
    *(u16x8*)&vrb[swoff] = v0;
    *(u16x8*)&vrb[swoff + 8] = v1;
  }
  __syncthreads();

  f32x16 sa0, sa1;  // group 1 carries S across the barrier; group 0 uses within-window
  const int NT2 = T_SEQ / 64 / 2;  // 16 tiles per half
  for (int t = 0; t < NT2; ++t) {
    const bool pre = (t + 1 < NT2);
    u16x8 kn0, kn1, vn0, vn1;
    if (pre) {  // issue next-tile global loads early (written to LDS post-B1)
      const unsigned short* ks = kseg + (size_t)(t + 1) * (64 * DH);
      kn0 = *(const u16x8*)ks;
      kn1 = *(const u16x8*)(ks + 8);
      const unsigned short* vs = vseg + (size_t)(t + 1) * 64;
      vn0 = *(const u16x8*)vs;
      vn1 = *(const u16x8*)(vs + 8);
    }
    // window A: half 0 -> QK(t);  half 1 -> SM+PV(t-1) (V tile t-1 lives in vab)
    if (half == 0) {
      qk(krb, sa0, sa1);
    } else if (t > 0) {
      smpv(sa0, sa1, vab);
    }
    __syncthreads();  // B1: swap roles
    // window B: half 0 -> SM+PV(t) (V tile t in vrb);  half 1 -> QK(t)
    if (half == 0) {
      smpv(sa0, sa1, vrb);
    } else {
      qk(krb, sa0, sa1);
    }
    if (pre) {  // stage tile t+1 into alt buffers
      *(u16x8*)&kab[swoff] = kn0;
      *(u16x8*)&kab[swoff + 8] = kn1;
      *(u16x8*)&vab[swoff] = vn0;
      *(u16x8*)&vab[swoff + 8] = vn1;
    }
    __syncthreads();  // B2: alt buffers ready; swap
    unsigned short* tp;
    tp = krb; krb = kab; kab = tp;
    tp = vrb; vrb = vab; vab = tp;
  }
  if (half == 1) smpv(sa0, sa1, vab);  // finish last tile (V(15) in vab after final swap)

  // ---- merge halves: exact (no max tracking): O += O_partner, l += l_partner ----
  float* mbuf = (float*)&Kl[0][0][0];  // 4 waves x 2112 floats = 33.8KB (within Kl[0] = 36.9KB)
  const int MS = 2112;
  if (half == 1) {
    float* mb = mbuf + (wave - 4) * MS;
#pragma unroll
    for (int r = 0; r < 16; ++r) mb[r * 64 + lane] = oacc0[r];
#pragma unroll
    for (int r = 0; r < 16; ++r) mb[1024 + r * 64 + lane] = oacc1[r];
    mb[2048 + lane] = l_run;
  }
  __syncthreads();
  if (half == 0) {
    float* mb = mbuf + wave * MS;
#pragma unroll
    for (int r = 0; r < 16; ++r) oacc0[r] += mb[r * 64 + lane];
#pragma unroll
    for (int r = 0; r < 16; ++r) oacc1[r] += mb[1024 + r * 64 + lane];
    l_run += mb[2048 + lane];

    // ---- epilogue: normalize (l via shfl) and store ----
    const int n = nh >> 3, h = nh & 7;
    const size_t obase = (size_t)(n * COUT + h * DH) * T_SEQ;
    const int d0 = ln, d1 = 32 + ln;
#pragma unroll
    for (int rq = 0; rq < 4; ++rq) {
      const int tbase = tq0 + 8 * rq + 4 * hi;
      f32x4 o0, o1;
#pragma unroll
      for (int j = 0; j < 4; ++j) {
        const float lv = __shfl(l_run, 8 * rq + 4 * hi + j);
        const float inv = __builtin_amdgcn_rcpf(lv);
        o0[j] = oacc0[4 * rq + j] * inv;
        o1[j] = oacc1[4 * rq + j] * inv;
      }
      *(f32x4*)&outp[obase + (size_t)d0 * T_SEQ + tbase] = o0;
      *(f32x4*)&outp[obase + (size_t)d1 * T_SEQ + tbase] = o1;
    }
  }
}

extern "C" void kernel_launch(void* const* d_in, const int* in_sizes, int n_in,
                              void* d_out, int out_size, void* d_ws, size_t ws_size,
                              hipStream_t stream) {
  (void)in_sizes; (void)n_in; (void)out_size; (void)ws_size;
  const float* x  = (const float*)d_in[0];
  const float* Wq = (const float*)d_in[1];
  const float* Wk = (const float*)d_in[2];
  const float* Wv = (const float*)d_in[3];
  float* outp = (float*)d_out;

  char* ws = (char*)d_ws;
  unsigned short* wb = (unsigned short*)ws;                       // 786432 B
  unsigned short* xT = (unsigned short*)(ws + 786432);            // 4194304 B
  unsigned short* qb = (unsigned short*)(ws + 4980736);           // 8388608 B each
  unsigned short* kb = qb + 4194304;
  unsigned short* vb = kb + 4194304;                              // vb is d-major [nh][64][2048]

  pack_w_k<<<1536, 256, 0, stream>>>(Wq, Wk, Wv, wb);
  pack_xT_k<<<dim3(32, 4, 4), 256, 0, stream>>>(x, xT);
  proj_k<<<dim3(8, 16, 12), 256, 0, stream>>>(wb, xT, qb, kb, vb);
  attn_k<<<512, 512, 0, stream>>>(qb, kb, vb, outp);
}

// Round 11
// 112.059 us; speedup vs baseline: 1.0104x; 1.0104x over previous
//
#include <hip/hip_runtime.h>
#include <stdint.h>

#define T_SEQ 2048
#define CIN 256
#define COUT 512
#define NHEAD 8
#define DH 64
#define LROW 72  // LDS row stride in elems (144B: 16B-aligned, 9 granules -> even bank spread)

typedef __bf16 bf16x8 __attribute__((ext_vector_type(8)));
typedef float f32x4 __attribute__((ext_vector_type(4)));
typedef float f32x16 __attribute__((ext_vector_type(16)));
typedef unsigned short u16x8 __attribute__((ext_vector_type(8)));
typedef unsigned u32x4 __attribute__((ext_vector_type(4)));

static __device__ __forceinline__ unsigned short bf16_rne(float f) {
  unsigned u = __builtin_bit_cast(unsigned, f);
  u += 0x7FFFu + ((u >> 16) & 1u);
  return (unsigned short)(u >> 16);
}

static __device__ __forceinline__ unsigned cvt_pk_bf16(float lo, float hi) {
  unsigned r;
  asm("v_cvt_pk_bf16_f32 %0, %1, %2" : "=v"(r) : "v"(lo), "v"(hi));
  return r;
}

// in-place cross-half swap (T12)
static __device__ __forceinline__ void plswap(unsigned& a, unsigned& b) {
  auto rr = __builtin_amdgcn_permlane32_swap((int)a, (int)b, false, false);
  a = (unsigned)rr[0];
  b = (unsigned)rr[1];
}

static __device__ __forceinline__ bf16x8 ld_frag(const unsigned short* p) {
  u16x8 v = *(const u16x8*)p;
  return __builtin_bit_cast(bf16x8, v);
}

// ---------------- pack: weights f32 -> bf16 ----------------
__global__ __launch_bounds__(256) void pack_w_k(const float* __restrict__ wq,
                                                const float* __restrict__ wk,
                                                const float* __restrict__ wv,
                                                unsigned short* __restrict__ wb) {
  int i = blockIdx.x * 256 + threadIdx.x;
  const float* src = (i < 131072) ? wq : (i < 262144) ? wk : wv;
  wb[i] = bf16_rne(src[i & 131071]);
}

// ---------------- pack: x (n,c,t) f32 -> xT (n,t,c) bf16 ----------------
__global__ __launch_bounds__(256) void pack_xT_k(const float* __restrict__ x,
                                                 unsigned short* __restrict__ xT) {
  __shared__ float tile[64][65];
  const int n = blockIdx.z, c0 = blockIdx.y * 64, t0 = blockIdx.x * 64;
  const int i = threadIdx.x;
  {
    const int cc = i >> 2, tch = (i & 3) * 16;
    const float* src = x + ((size_t)n * CIN + c0 + cc) * T_SEQ + t0 + tch;
    const float4* s4 = (const float4*)src;
#pragma unroll
    for (int q = 0; q < 4; ++q) {
      float4 v = s4[q];
      tile[cc][tch + q * 4 + 0] = v.x;
      tile[cc][tch + q * 4 + 1] = v.y;
      tile[cc][tch + q * 4 + 2] = v.z;
      tile[cc][tch + q * 4 + 3] = v.w;
    }
  }
  __syncthreads();
  {
    const int tt = i >> 2, cch = (i & 3) * 16;
    unsigned short* dst = xT + ((size_t)n * T_SEQ + t0 + tt) * CIN + c0 + cch;
    u16x8 w0, w1;
#pragma unroll
    for (int j = 0; j < 8; ++j) w0[j] = bf16_rne(tile[cch + j][tt]);
#pragma unroll
    for (int j = 0; j < 8; ++j) w1[j] = bf16_rne(tile[cch + 8 + j][tt]);
    *(u16x8*)dst = w0;
    *(u16x8*)(dst + 8) = w1;
  }
}

// ---------------- projection: all 3 W's per block; X frags cached in regs ----------------
// grid (8 o-tiles, 16 t-tiles, 4 n), block 256 (4 waves, 32 t each)
__global__ __launch_bounds__(256) void proj_k(const unsigned short* __restrict__ wb,
                                              const unsigned short* __restrict__ xT,
                                              unsigned short* __restrict__ qb,
                                              unsigned short* __restrict__ kb,
                                              unsigned short* __restrict__ vb) {
  __shared__ unsigned short vt_lds[64][136];  // 64 o x 128 t, stride 136
  const int n = blockIdx.z;
  const unsigned short* X = xT + (size_t)n * T_SEQ * CIN;
  const int tid = threadIdx.x, wave = tid >> 6, lane = tid & 63;
  const int c = lane & 15, g = lane >> 4;
  const int o0 = blockIdx.x * 64;
  const int t0 = blockIdx.y * 128 + wave * 32;

  // cache all X fragments for this wave's 32 t rows (16 x bf16x8 = 64 VGPR)
  bf16x8 a[8][2];
#pragma unroll
  for (int k8 = 0; k8 < 8; ++k8)
#pragma unroll
    for (int mt = 0; mt < 2; ++mt)
      a[k8][mt] = ld_frag(X + (size_t)(t0 + mt * 16 + c) * CIN + k8 * 32 + g * 8);

  const f32x4 z4 = {0.f, 0.f, 0.f, 0.f};
  const int h = o0 >> 6;
  const size_t base = ((size_t)(n * NHEAD + h)) * T_SEQ * DH;

  for (int w = 0; w < 3; ++w) {
    const unsigned short* W = wb + (size_t)w * COUT * CIN;
    f32x4 acc[2][4];
#pragma unroll
    for (int mt = 0; mt < 2; ++mt)
#pragma unroll
      for (int no = 0; no < 4; ++no) acc[mt][no] = z4;

#pragma unroll
    for (int k8 = 0; k8 < 8; ++k8) {
      bf16x8 b[4];
#pragma unroll
      for (int no = 0; no < 4; ++no)
        b[no] = ld_frag(W + (size_t)(o0 + no * 16 + c) * CIN + k8 * 32 + g * 8);
#pragma unroll
      for (int mt = 0; mt < 2; ++mt)
#pragma unroll
        for (int no = 0; no < 4; ++no)
          acc[mt][no] = __builtin_amdgcn_mfma_f32_16x16x32_bf16(a[k8][mt], b[no], acc[mt][no], 0, 0, 0);
    }

    if (w == 2) {
      // V: stage to LDS d-major, then coalesced global store
#pragma unroll
      for (int mt = 0; mt < 2; ++mt)
#pragma unroll
        for (int no = 0; no < 4; ++no) {
          const int d = no * 16 + c;
          const int lt = (wave * 32) + mt * 16 + 4 * g;
#pragma unroll
          for (int pr = 0; pr < 2; ++pr) {
            const unsigned pw = (unsigned)bf16_rne(acc[mt][no][2 * pr]) |
                                ((unsigned)bf16_rne(acc[mt][no][2 * pr + 1]) << 16);
            *(unsigned*)&vt_lds[d][lt + 2 * pr] = pw;
          }
        }
      __syncthreads();
      const int row = tid >> 2, seg = tid & 3;
      unsigned short* dst = vb + base + (size_t)row * T_SEQ + blockIdx.y * 128 + seg * 32;
      const unsigned short* srcl = &vt_lds[row][seg * 32];
#pragma unroll
      for (int q = 0; q < 4; ++q) *(u16x8*)(dst + q * 8) = *(const u16x8*)(srcl + q * 8);
    } else {
      unsigned short* dst = (w == 0) ? qb : kb;
      // fold 1/sqrt(dk) * log2(e) into q so attention uses exp2 directly
      const float scale = (w == 0) ? 0.18033688011112043f : 1.0f;
#pragma unroll
      for (int mt = 0; mt < 2; ++mt)
#pragma unroll
        for (int no = 0; no < 4; ++no)
#pragma unroll
          for (int r = 0; r < 4; ++r) {
            const int t = t0 + mt * 16 + 4 * g + r;
            const int d = no * 16 + c;
            dst[base + (size_t)t * DH + d] = bf16_rne(acc[mt][no][r] * scale);
          }
    }
  }
}

// ---------------- flash attention: 2-wave blocks, 4 independent blocks/CU ----------------
// grid 1024 (XCD-swizzled -> 32 tq-tiles x 32 nh), block 128 (2 waves x 32 tq). KV tile 64, dbuf.
// 32x32x16 MFMA; in-register softmax via cvt_pk + permlane32_swap; no max tracking (bounded).
__global__ __launch_bounds__(128) void attn_k(const unsigned short* __restrict__ qb,
                                              const unsigned short* __restrict__ kb,
                                              const unsigned short* __restrict__ vbt,
                                              float* __restrict__ outp) {
  __shared__ unsigned short Kl[2][64 * LROW];  // rows tk, d contiguous; stride 72
  __shared__ unsigned short Vt[2][64 * LROW];  // rows d, tk contiguous; stride 72

  // XCD-bijective swizzle: 1024 blocks, 8 XCDs -> 128 contiguous sids per XCD (4 nh panels)
  const int bid = blockIdx.x;
  const int sid = (bid & 7) * 128 + (bid >> 3);
  const int tqt = sid & 31, nh = sid >> 5;

  const int tid = threadIdx.x;
  const int wave = tid >> 6, lane = tid & 63;
  const int ln = lane & 31, hi = lane >> 5;
  const int tq0 = tqt * 64 + wave * 32;
  const unsigned short* Q = qb + (size_t)nh * T_SEQ * DH;
  const unsigned short* K = kb + (size_t)nh * T_SEQ * DH;   // [t][d]
  const unsigned short* V = vbt + (size_t)nh * T_SEQ * DH;  // [d][t]

  // Q fragments: B-operand, lane ln = tq col, k = d = dblk*16 + hi*8 + j
  bf16x8 qf[4];
#pragma unroll
  for (int dblk = 0; dblk < 4; ++dblk)
    qf[dblk] = ld_frag(Q + (size_t)(tq0 + ln) * DH + dblk * 16 + hi * 8);

  const f32x16 z16 = {0.f, 0.f, 0.f, 0.f, 0.f, 0.f, 0.f, 0.f,
                      0.f, 0.f, 0.f, 0.f, 0.f, 0.f, 0.f, 0.f};
  f32x16 oacc0 = z16, oacc1 = z16;  // O cols: oacc0 -> d=ln, oacc1 -> d=32+ln
  float l_run = 0.f;

  // ---- staging decomposition (128 threads, 32 elems each): row = tid&63, half = tid>>6 ----
  const int srow = tid & 63, shalf = tid >> 6;
  const unsigned short* kseg = K + (size_t)srow * DH + shalf * 32;     // +64*DH per tile
  const unsigned short* vseg = V + (size_t)srow * T_SEQ + shalf * 32;  // +64 per tile
  const int swoff = srow * LROW + shalf * 32;
  // read row offsets (elems)
  const int row0 = ln * LROW;
  const int row1 = (32 + ln) * LROW;
  const int hioff = hi * 8;

  // ---- prologue: stage tile 0 ----
  unsigned short* krb = &Kl[0][0];
  unsigned short* kab = &Kl[1][0];
  unsigned short* vrb = &Vt[0][0];
  unsigned short* vab = &Vt[1][0];
  {
    u16x8 k0 = *(const u16x8*)kseg;
    u16x8 k1 = *(const u16x8*)(kseg + 8);
    u16x8 k2 = *(const u16x8*)(kseg + 16);
    u16x8 k3 = *(const u16x8*)(kseg + 24);
    u16x8 v0 = *(const u16x8*)vseg;
    u16x8 v1 = *(const u16x8*)(vseg + 8);
    u16x8 v2 = *(const u16x8*)(vseg + 16);
    u16x8 v3 = *(const u16x8*)(vseg + 24);
    *(u16x8*)&krb[swoff] = k0;
    *(u16x8*)&krb[swoff + 8] = k1;
    *(u16x8*)&krb[swoff + 16] = k2;
    *(u16x8*)&krb[swoff + 24] = k3;
    *(u16x8*)&vrb[swoff] = v0;
    *(u16x8*)&vrb[swoff + 8] = v1;
    *(u16x8*)&vrb[swoff + 16] = v2;
    *(u16x8*)&vrb[swoff + 24] = v3;
  }
  __syncthreads();

  const int NT = T_SEQ / 64;
  for (int t = 0; t < NT; ++t) {
    const bool pre = (t + 1 < NT);
    u16x8 kn[4], vn[4];
    if (pre) {  // issue next-tile global loads early (written to LDS after PV)
      const unsigned short* ks = kseg + (size_t)(t + 1) * (64 * DH);
      const unsigned short* vs = vseg + (size_t)(t + 1) * 64;
#pragma unroll
      for (int j = 0; j < 4; ++j) {
        kn[j] = *(const u16x8*)(ks + j * 8);
        vn[j] = *(const u16x8*)(vs + j * 8);
      }
    }
    // ---- S = K x Q (A = K rows tk, B = Q cols tq), two tk-halves ----
    f32x16 sa0 = z16, sa1 = z16;
    __builtin_amdgcn_s_setprio(1);
#pragma unroll
    for (int dblk = 0; dblk < 4; ++dblk) {
      bf16x8 ka0 = ld_frag(krb + row0 + dblk * 16 + hioff);
      bf16x8 ka1 = ld_frag(krb + row1 + dblk * 16 + hioff);
      sa0 = __builtin_amdgcn_mfma_f32_32x32x16_bf16(ka0, qf[dblk], sa0, 0, 0, 0);
      sa1 = __builtin_amdgcn_mfma_f32_32x32x16_bf16(ka1, qf[dblk], sa1, 0, 0, 0);
    }
    __builtin_amdgcn_s_setprio(0);
    // ---- softmax numerator in-register: p = exp2(s); colsum; pack ----
    float p0[16], p1[16];
    float cs = 0.f;
#pragma unroll
    for (int r = 0; r < 16; ++r) {
      p0[r] = __builtin_amdgcn_exp2f(sa0[r]);
      p1[r] = __builtin_amdgcn_exp2f(sa1[r]);
      cs += p0[r] + p1[r];
    }
    cs += __shfl_xor(cs, 32);
    l_run += cs;
    unsigned W0[8], W1[8];
#pragma unroll
    for (int j = 0; j < 8; ++j) {
      W0[j] = cvt_pk_bf16(p0[2 * j], p0[2 * j + 1]);
      W1[j] = cvt_pk_bf16(p1[2 * j], p1[2 * j + 1]);
    }
    // ---- redistribute to PV A-fragments via permlane32_swap (T12) ----
    plswap(W0[0], W0[2]);
    plswap(W0[1], W0[3]);
    plswap(W0[4], W0[6]);
    plswap(W0[5], W0[7]);
    plswap(W1[0], W1[2]);
    plswap(W1[1], W1[3]);
    plswap(W1[4], W1[6]);
    plswap(W1[5], W1[7]);
    bf16x8 pa[4];
    {
      u32x4 f;
      f[0] = W0[0]; f[1] = W0[1]; f[2] = W0[2]; f[3] = W0[3];
      pa[0] = __builtin_bit_cast(bf16x8, f);
      f[0] = W0[4]; f[1] = W0[5]; f[2] = W0[6]; f[3] = W0[7];
      pa[1] = __builtin_bit_cast(bf16x8, f);
      f[0] = W1[0]; f[1] = W1[1]; f[2] = W1[2]; f[3] = W1[3];
      pa[2] = __builtin_bit_cast(bf16x8, f);
      f[0] = W1[4]; f[1] = W1[5]; f[2] = W1[6]; f[3] = W1[7];
      pa[3] = __builtin_bit_cast(bf16x8, f);
    }
    // ---- PV: O[tq][d] += P x V (A = P rows tq, B = V^T cols d from Vt rows) ----
    __builtin_amdgcn_s_setprio(1);
#pragma unroll
    for (int kbk = 0; kbk < 4; ++kbk) {
      bf16x8 vf0 = ld_frag(vrb + row0 + kbk * 16 + hioff);
      bf16x8 vf1 = ld_frag(vrb + row1 + kbk * 16 + hioff);
      oacc0 = __builtin_amdgcn_mfma_f32_32x32x16_bf16(pa[kbk], vf0, oacc0, 0, 0, 0);
      oacc1 = __builtin_amdgcn_mfma_f32_32x32x16_bf16(pa[kbk], vf1, oacc1, 0, 0, 0);
    }
    __builtin_amdgcn_s_setprio(0);
    // ---- write next K/V tiles into alt buffers ----
    if (pre) {
#pragma unroll
      for (int j = 0; j < 4; ++j) {
        *(u16x8*)&kab[swoff + j * 8] = kn[j];
        *(u16x8*)&vab[swoff + j * 8] = vn[j];
      }
    }
    __syncthreads();
    unsigned short* tp;
    tp = krb; krb = kab; kab = tp;
    tp = vrb; vrb = vab; vab = tp;
  }

  // ---- epilogue: l via shfl, normalize, store ----
  const int n = nh >> 3, h = nh & 7;
  const size_t obase = (size_t)(n * COUT + h * DH) * T_SEQ;
  const int d0 = ln, d1 = 32 + ln;
#pragma unroll
  for (int rq = 0; rq < 4; ++rq) {
    const int tbase = tq0 + 8 * rq + 4 * hi;
    f32x4 o0, o1;
#pragma unroll
    for (int j = 0; j < 4; ++j) {
      const float lv = __shfl(l_run, 8 * rq + 4 * hi + j);
      const float inv = __builtin_amdgcn_rcpf(lv);
      o0[j] = oacc0[4 * rq + j] * inv;
      o1[j] = oacc1[4 * rq + j] * inv;
    }
    *(f32x4*)&outp[obase + (size_t)d0 * T_SEQ + tbase] = o0;
    *(f32x4*)&outp[obase + (size_t)d1 * T_SEQ + tbase] = o1;
  }
}

extern "C" void kernel_launch(void* const* d_in, const int* in_sizes, int n_in,
                              void* d_out, int out_size, void* d_ws, size_t ws_size,
                              hipStream_t stream) {
  (void)in_sizes; (void)n_in; (void)out_size; (void)ws_size;
  const float* x  = (const float*)d_in[0];
  const float* Wq = (const float*)d_in[1];
  const float* Wk = (const float*)d_in[2];
  const float* Wv = (const float*)d_in[3];
  float* outp = (float*)d_out;

  char* ws = (char*)d_ws;
  unsigned short* wb = (unsigned short*)ws;                       // 786432 B
  unsigned short* xT = (unsigned short*)(ws + 786432);            // 4194304 B
  unsigned short* qb = (unsigned short*)(ws + 4980736);           // 8388608 B each
  unsigned short* kb = qb + 4194304;
  unsigned short* vb = kb + 4194304;                              // vb is d-major [nh][64][2048]

  pack_w_k<<<1536, 256, 0, stream>>>(Wq, Wk, Wv, wb);
  pack_xT_k<<<dim3(32, 4, 4), 256, 0, stream>>>(x, xT);
  proj_k<<<dim3(8, 16, 4), 256, 0, stream>>>(wb, xT, qb, kb, vb);
  attn_k<<<1024, 128, 0, stream>>>(qb, kb, vb, outp);
}

// Round 12
// 87.224 us; speedup vs baseline: 1.2981x; 1.2847x over previous
//
#include <hip/hip_runtime.h>
#include <stdint.h>

#define T_SEQ 2048
#define CIN 256
#define COUT 512
#define NHEAD 8
#define DH 64
#define LROW 72  // LDS row stride in elems (144B: 16B-aligned, 9 granules -> even bank spread)

typedef __bf16 bf16x8 __attribute__((ext_vector_type(8)));
typedef float f32x4 __attribute__((ext_vector_type(4)));
typedef float f32x16 __attribute__((ext_vector_type(16)));
typedef unsigned short u16x8 __attribute__((ext_vector_type(8)));
typedef unsigned u32x4 __attribute__((ext_vector_type(4)));

static __device__ __forceinline__ unsigned short bf16_rne(float f) {
  unsigned u = __builtin_bit_cast(unsigned, f);
  u += 0x7FFFu + ((u >> 16) & 1u);
  return (unsigned short)(u >> 16);
}

static __device__ __forceinline__ unsigned cvt_pk_bf16(float lo, float hi) {
  unsigned r;
  asm("v_cvt_pk_bf16_f32 %0, %1, %2" : "=v"(r) : "v"(lo), "v"(hi));
  return r;
}

// in-place cross-half swap (T12)
static __device__ __forceinline__ void plswap(unsigned& a, unsigned& b) {
  auto rr = __builtin_amdgcn_permlane32_swap((int)a, (int)b, false, false);
  a = (unsigned)rr[0];
  b = (unsigned)rr[1];
}

static __device__ __forceinline__ bf16x8 ld_frag(const unsigned short* p) {
  u16x8 v = *(const u16x8*)p;
  return __builtin_bit_cast(bf16x8, v);
}

// ---------------- pack: weights f32 -> bf16 ----------------
__global__ __launch_bounds__(256) void pack_w_k(const float* __restrict__ wq,
                                                const float* __restrict__ wk,
                                                const float* __restrict__ wv,
                                                unsigned short* __restrict__ wb) {
  int i = blockIdx.x * 256 + threadIdx.x;
  const float* src = (i < 131072) ? wq : (i < 262144) ? wk : wv;
  wb[i] = bf16_rne(src[i & 131071]);
}

// ---------------- pack: x (n,c,t) f32 -> xT (n,t,c) bf16 ----------------
__global__ __launch_bounds__(256) void pack_xT_k(const float* __restrict__ x,
                                                 unsigned short* __restrict__ xT) {
  __shared__ float tile[64][65];
  const int n = blockIdx.z, c0 = blockIdx.y * 64, t0 = blockIdx.x * 64;
  const int i = threadIdx.x;
  {
    const int cc = i >> 2, tch = (i & 3) * 16;
    const float* src = x + ((size_t)n * CIN + c0 + cc) * T_SEQ + t0 + tch;
    const float4* s4 = (const float4*)src;
#pragma unroll
    for (int q = 0; q < 4; ++q) {
      float4 v = s4[q];
      tile[cc][tch + q * 4 + 0] = v.x;
      tile[cc][tch + q * 4 + 1] = v.y;
      tile[cc][tch + q * 4 + 2] = v.z;
      tile[cc][tch + q * 4 + 3] = v.w;
    }
  }
  __syncthreads();
  {
    const int tt = i >> 2, cch = (i & 3) * 16;
    unsigned short* dst = xT + ((size_t)n * T_SEQ + t0 + tt) * CIN + c0 + cch;
    u16x8 w0, w1;
#pragma unroll
    for (int j = 0; j < 8; ++j) w0[j] = bf16_rne(tile[cch + j][tt]);
#pragma unroll
    for (int j = 0; j < 8; ++j) w1[j] = bf16_rne(tile[cch + 8 + j][tt]);
    *(u16x8*)dst = w0;
    *(u16x8*)(dst + 8) = w1;
  }
}

// ---------------- projection: all 3 W's per block; X frags cached in regs ----------------
// grid (8 o-tiles, 16 t-tiles, 4 n), block 256 (4 waves, 32 t each)
__global__ __launch_bounds__(256) void proj_k(const unsigned short* __restrict__ wb,
                                              const unsigned short* __restrict__ xT,
                                              unsigned short* __restrict__ qb,
                                              unsigned short* __restrict__ kb,
                                              unsigned short* __restrict__ vb) {
  __shared__ unsigned short vt_lds[64][136];  // 64 o x 128 t, stride 136
  const int n = blockIdx.z;
  const unsigned short* X = xT + (size_t)n * T_SEQ * CIN;
  const int tid = threadIdx.x, wave = tid >> 6, lane = tid & 63;
  const int c = lane & 15, g = lane >> 4;
  const int o0 = blockIdx.x * 64;
  const int t0 = blockIdx.y * 128 + wave * 32;

  // cache all X fragments for this wave's 32 t rows (16 x bf16x8 = 64 VGPR)
  bf16x8 a[8][2];
#pragma unroll
  for (int k8 = 0; k8 < 8; ++k8)
#pragma unroll
    for (int mt = 0; mt < 2; ++mt)
      a[k8][mt] = ld_frag(X + (size_t)(t0 + mt * 16 + c) * CIN + k8 * 32 + g * 8);

  const f32x4 z4 = {0.f, 0.f, 0.f, 0.f};
  const int h = o0 >> 6;
  const size_t base = ((size_t)(n * NHEAD + h)) * T_SEQ * DH;

  for (int w = 0; w < 3; ++w) {
    const unsigned short* W = wb + (size_t)w * COUT * CIN;
    f32x4 acc[2][4];
#pragma unroll
    for (int mt = 0; mt < 2; ++mt)
#pragma unroll
      for (int no = 0; no < 4; ++no) acc[mt][no] = z4;

#pragma unroll
    for (int k8 = 0; k8 < 8; ++k8) {
      bf16x8 b[4];
#pragma unroll
      for (int no = 0; no < 4; ++no)
        b[no] = ld_frag(W + (size_t)(o0 + no * 16 + c) * CIN + k8 * 32 + g * 8);
#pragma unroll
      for (int mt = 0; mt < 2; ++mt)
#pragma unroll
        for (int no = 0; no < 4; ++no)
          acc[mt][no] = __builtin_amdgcn_mfma_f32_16x16x32_bf16(a[k8][mt], b[no], acc[mt][no], 0, 0, 0);
    }

    if (w == 2) {
      // V: stage to LDS d-major, then coalesced global store
#pragma unroll
      for (int mt = 0; mt < 2; ++mt)
#pragma unroll
        for (int no = 0; no < 4; ++no) {
          const int d = no * 16 + c;
          const int lt = (wave * 32) + mt * 16 + 4 * g;
#pragma unroll
          for (int pr = 0; pr < 2; ++pr) {
            const unsigned pw = (unsigned)bf16_rne(acc[mt][no][2 * pr]) |
                                ((unsigned)bf16_rne(acc[mt][no][2 * pr + 1]) << 16);
            *(unsigned*)&vt_lds[d][lt + 2 * pr] = pw;
          }
        }
      __syncthreads();
      const int row = tid >> 2, seg = tid & 3;
      unsigned short* dst = vb + base + (size_t)row * T_SEQ + blockIdx.y * 128 + seg * 32;
      const unsigned short* srcl = &vt_lds[row][seg * 32];
#pragma unroll
      for (int q = 0; q < 4; ++q) *(u16x8*)(dst + q * 8) = *(const u16x8*)(srcl + q * 8);
    } else {
      unsigned short* dst = (w == 0) ? qb : kb;
      // fold 1/sqrt(dk) * log2(e) into q so attention uses exp2 directly
      const float scale = (w == 0) ? 0.18033688011112043f : 1.0f;
#pragma unroll
      for (int mt = 0; mt < 2; ++mt)
#pragma unroll
        for (int no = 0; no < 4; ++no)
#pragma unroll
          for (int r = 0; r < 4; ++r) {
            const int t = t0 + mt * 16 + 4 * g + r;
            const int d = no * 16 + c;
            dst[base + (size_t)t * DH + d] = bf16_rne(acc[mt][no][r] * scale);
          }
    }
  }
}

// ---------------- flash attention: QBLK=64/wave, 8 waves (tk-split 2 halves), LDS dbuf ----------------
// grid 256 (XCD-swizzled -> 8 tq-tiles x 32 nh), block 512. Each wave: 64 tq, so one set of
// K/V fragment reads serves 2 tq-subtiles -> LDS fragment traffic halved vs QBLK=32.
// 32x32x16 MFMA; in-register softmax (cvt_pk + permlane32_swap); no max tracking (bounded);
// exact end-merge: O = O_a + O_b, l = l_a + l_b.
__global__ __launch_bounds__(512) void attn_k(const unsigned short* __restrict__ qb,
                                              const unsigned short* __restrict__ kb,
                                              const unsigned short* __restrict__ vbt,
                                              float* __restrict__ outp) {
  // carved union: per half {K dbuf 2x4608, V dbuf 2x4608} elems; merge buffer reuses all
  __shared__ unsigned short smem[4 * 2 * 4608];  // 73728 B

  // XCD-bijective swizzle: 256 blocks, 8 XCDs -> 32 contiguous sids per XCD
  const int bid = blockIdx.x;
  const int sid = (bid & 7) * 32 + (bid >> 3);
  const int tqt = sid & 7, nh = sid >> 3;

  const int tid = threadIdx.x;
  const int wave = tid >> 6, lane = tid & 63;
  const int half = wave >> 2;  // tk half: 0 -> [0,1024), 1 -> [1024,2048)
  const int ln = lane & 31, hi = lane >> 5;
  const int tq0 = tqt * 256 + (wave & 3) * 64;
  const unsigned short* Q = qb + (size_t)nh * T_SEQ * DH;
  const unsigned short* K = kb + (size_t)nh * T_SEQ * DH;   // [t][d]
  const unsigned short* V = vbt + (size_t)nh * T_SEQ * DH;  // [d][t]

  // Q fragments for both tq-subs: B-operand, lane ln = tq col
  bf16x8 qf0[4], qf1[4];
#pragma unroll
  for (int dblk = 0; dblk < 4; ++dblk) {
    qf0[dblk] = ld_frag(Q + (size_t)(tq0 + ln) * DH + dblk * 16 + hi * 8);
    qf1[dblk] = ld_frag(Q + (size_t)(tq0 + 32 + ln) * DH + dblk * 16 + hi * 8);
  }

  const f32x16 z16 = {0.f, 0.f, 0.f, 0.f, 0.f, 0.f, 0.f, 0.f,
                      0.f, 0.f, 0.f, 0.f, 0.f, 0.f, 0.f, 0.f};
  f32x16 oacc00 = z16, oacc01 = z16;  // sub0: d=ln, d=32+ln
  f32x16 oacc10 = z16, oacc11 = z16;  // sub1
  float l_run0 = 0.f, l_run1 = 0.f;

  // ---- staging decomposition within half (256 threads): row = ht&63, seg = ht>>6 ----
  const int ht = tid & 255;
  const int srow = ht & 63, sseg = ht >> 6;
  const unsigned short* kseg = K + (size_t)(half * 1024 + srow) * DH + sseg * 16;  // +64*DH/tile
  const unsigned short* vseg = V + (size_t)srow * T_SEQ + half * 1024 + sseg * 16; // +64/tile
  const int swoff = srow * LROW + sseg * 16;
  // read row offsets (elems)
  const int row0 = ln * LROW;
  const int row1 = (32 + ln) * LROW;
  const int hioff = hi * 8;

  // ---- prologue: stage tile 0 of this half ----
  unsigned short* krb = smem + half * 18432;
  unsigned short* kab = krb + 4608;
  unsigned short* vrb = krb + 9216;
  unsigned short* vab = krb + 13824;
  {
    u16x8 k0 = *(const u16x8*)kseg;
    u16x8 k1 = *(const u16x8*)(kseg + 8);
    u16x8 v0 = *(const u16x8*)vseg;
    u16x8 v1 = *(const u16x8*)(vseg + 8);
    *(u16x8*)&krb[swoff] = k0;
    *(u16x8*)&krb[swoff + 8] = k1;
    *(u16x8*)&vrb[swoff] = v0;
    *(u16x8*)&vrb[swoff + 8] = v1;
  }
  __syncthreads();

  const int NT2 = T_SEQ / 64 / 2;  // 16 tiles per half
  for (int t = 0; t < NT2; ++t) {
    const bool pre = (t + 1 < NT2);
    u16x8 kn0, kn1, vn0, vn1;
    if (pre) {  // issue next-tile global loads early (written to LDS after PV)
      const unsigned short* ks = kseg + (size_t)(t + 1) * (64 * DH);
      kn0 = *(const u16x8*)ks;
      kn1 = *(const u16x8*)(ks + 8);
      const unsigned short* vs = vseg + (size_t)(t + 1) * 64;
      vn0 = *(const u16x8*)vs;
      vn1 = *(const u16x8*)(vs + 8);
    }
    // ---- S = K x Q: K frags shared across both tq-subs ----
    f32x16 sa00 = z16, sa01 = z16, sa10 = z16, sa11 = z16;
    __builtin_amdgcn_s_setprio(1);
#pragma unroll
    for (int dblk = 0; dblk < 4; ++dblk) {
      bf16x8 ka0 = ld_frag(krb + row0 + dblk * 16 + hioff);
      bf16x8 ka1 = ld_frag(krb + row1 + dblk * 16 + hioff);
      sa00 = __builtin_amdgcn_mfma_f32_32x32x16_bf16(ka0, qf0[dblk], sa00, 0, 0, 0);
      sa01 = __builtin_amdgcn_mfma_f32_32x32x16_bf16(ka1, qf0[dblk], sa01, 0, 0, 0);
      sa10 = __builtin_amdgcn_mfma_f32_32x32x16_bf16(ka0, qf1[dblk], sa10, 0, 0, 0);
      sa11 = __builtin_amdgcn_mfma_f32_32x32x16_bf16(ka1, qf1[dblk], sa11, 0, 0, 0);
    }
    __builtin_amdgcn_s_setprio(0);
    // ---- softmax numerators in-register, both subs ----
    bf16x8 pa0[4], pa1[4];
    {
      float p0[16], p1[16];
      float cs = 0.f;
#pragma unroll
      for (int r = 0; r < 16; ++r) {
        p0[r] = __builtin_amdgcn_exp2f(sa00[r]);
        p1[r] = __builtin_amdgcn_exp2f(sa01[r]);
        cs += p0[r] + p1[r];
      }
      cs += __shfl_xor(cs, 32);
      l_run0 += cs;
      unsigned W0[8], W1[8];
#pragma unroll
      for (int j = 0; j < 8; ++j) {
        W0[j] = cvt_pk_bf16(p0[2 * j], p0[2 * j + 1]);
        W1[j] = cvt_pk_bf16(p1[2 * j], p1[2 * j + 1]);
      }
      plswap(W0[0], W0[2]); plswap(W0[1], W0[3]);
      plswap(W0[4], W0[6]); plswap(W0[5], W0[7]);
      plswap(W1[0], W1[2]); plswap(W1[1], W1[3]);
      plswap(W1[4], W1[6]); plswap(W1[5], W1[7]);
      u32x4 f;
      f[0] = W0[0]; f[1] = W0[1]; f[2] = W0[2]; f[3] = W0[3];
      pa0[0] = __builtin_bit_cast(bf16x8, f);
      f[0] = W0[4]; f[1] = W0[5]; f[2] = W0[6]; f[3] = W0[7];
      pa0[1] = __builtin_bit_cast(bf16x8, f);
      f[0] = W1[0]; f[1] = W1[1]; f[2] = W1[2]; f[3] = W1[3];
      pa0[2] = __builtin_bit_cast(bf16x8, f);
      f[0] = W1[4]; f[1] = W1[5]; f[2] = W1[6]; f[3] = W1[7];
      pa0[3] = __builtin_bit_cast(bf16x8, f);
    }
    {
      float p0[16], p1[16];
      float cs = 0.f;
#pragma unroll
      for (int r = 0; r < 16; ++r) {
        p0[r] = __builtin_amdgcn_exp2f(sa10[r]);
        p1[r] = __builtin_amdgcn_exp2f(sa11[r]);
        cs += p0[r] + p1[r];
      }
      cs += __shfl_xor(cs, 32);
      l_run1 += cs;
      unsigned W0[8], W1[8];
#pragma unroll
      for (int j = 0; j < 8; ++j) {
        W0[j] = cvt_pk_bf16(p0[2 * j], p0[2 * j + 1]);
        W1[j] = cvt_pk_bf16(p1[2 * j], p1[2 * j + 1]);
      }
      plswap(W0[0], W0[2]); plswap(W0[1], W0[3]);
      plswap(W0[4], W0[6]); plswap(W0[5], W0[7]);
      plswap(W1[0], W1[2]); plswap(W1[1], W1[3]);
      plswap(W1[4], W1[6]); plswap(W1[5], W1[7]);
      u32x4 f;
      f[0] = W0[0]; f[1] = W0[1]; f[2] = W0[2]; f[3] = W0[3];
      pa1[0] = __builtin_bit_cast(bf16x8, f);
      f[0] = W0[4]; f[1] = W0[5]; f[2] = W0[6]; f[3] = W0[7];
      pa1[1] = __builtin_bit_cast(bf16x8, f);
      f[0] = W1[0]; f[1] = W1[1]; f[2] = W1[2]; f[3] = W1[3];
      pa1[2] = __builtin_bit_cast(bf16x8, f);
      f[0] = W1[4]; f[1] = W1[5]; f[2] = W1[6]; f[3] = W1[7];
      pa1[3] = __builtin_bit_cast(bf16x8, f);
    }
    // ---- PV: V frags shared across both tq-subs ----
    __builtin_amdgcn_s_setprio(1);
#pragma unroll
    for (int kbk = 0; kbk < 4; ++kbk) {
      bf16x8 vf0 = ld_frag(vrb + row0 + kbk * 16 + hioff);
      bf16x8 vf1 = ld_frag(vrb + row1 + kbk * 16 + hioff);
      oacc00 = __builtin_amdgcn_mfma_f32_32x32x16_bf16(pa0[kbk], vf0, oacc00, 0, 0, 0);
      oacc01 = __builtin_amdgcn_mfma_f32_32x32x16_bf16(pa0[kbk], vf1, oacc01, 0, 0, 0);
      oacc10 = __builtin_amdgcn_mfma_f32_32x32x16_bf16(pa1[kbk], vf0, oacc10, 0, 0, 0);
      oacc11 = __builtin_amdgcn_mfma_f32_32x32x16_bf16(pa1[kbk], vf1, oacc11, 0, 0, 0);
    }
    __builtin_amdgcn_s_setprio(0);
    // ---- write next K/V tiles into alt buffers ----
    if (pre) {
      *(u16x8*)&kab[swoff] = kn0;
      *(u16x8*)&kab[swoff + 8] = kn1;
      *(u16x8*)&vab[swoff] = vn0;
      *(u16x8*)&vab[swoff + 8] = vn1;
    }
    __syncthreads();
    unsigned short* tp;
    tp = krb; krb = kab; kab = tp;
    tp = vrb; vrb = vab; vab = tp;
  }

  // ---- merge halves: exact (no max tracking): O += O_partner, l += l_partner ----
  float* mbuf = (float*)smem;  // 4 regions x 4224 f32 = 67584 B <= 73728 B
  const int MS = 4224;
  if (half == 1) {
    float* mb = mbuf + (wave - 4) * MS;
#pragma unroll
    for (int r = 0; r < 16; ++r) mb[r * 64 + lane] = oacc00[r];
#pragma unroll
    for (int r = 0; r < 16; ++r) mb[1024 + r * 64 + lane] = oacc01[r];
#pragma unroll
    for (int r = 0; r < 16; ++r) mb[2048 + r * 64 + lane] = oacc10[r];
#pragma unroll
    for (int r = 0; r < 16; ++r) mb[3072 + r * 64 + lane] = oacc11[r];
    mb[4096 + lane] = l_run0;
    mb[4160 + lane] = l_run1;
  }
  __syncthreads();
  if (half == 0) {
    float* mb = mbuf + wave * MS;
#pragma unroll
    for (int r = 0; r < 16; ++r) oacc00[r] += mb[r * 64 + lane];
#pragma unroll
    for (int r = 0; r < 16; ++r) oacc01[r] += mb[1024 + r * 64 + lane];
#pragma unroll
    for (int r = 0; r < 16; ++r) oacc10[r] += mb[2048 + r * 64 + lane];
#pragma unroll
    for (int r = 0; r < 16; ++r) oacc11[r] += mb[3072 + r * 64 + lane];
    l_run0 += mb[4096 + lane];
    l_run1 += mb[4160 + lane];

    // ---- epilogue: normalize (l via shfl) and store, both subs ----
    const int n = nh >> 3, h = nh & 7;
    const size_t obase = (size_t)(n * COUT + h * DH) * T_SEQ;
    const int d0 = ln, d1 = 32 + ln;
#pragma unroll
    for (int rq = 0; rq < 4; ++rq) {
      const int tbase = tq0 + 8 * rq + 4 * hi;
      f32x4 o0, o1, o2, o3;
#pragma unroll
      for (int j = 0; j < 4; ++j) {
        const float lv0 = __shfl(l_run0, 8 * rq + 4 * hi + j);
        const float inv0 = __builtin_amdgcn_rcpf(lv0);
        const float lv1 = __shfl(l_run1, 8 * rq + 4 * hi + j);
        const float inv1 = __builtin_amdgcn_rcpf(lv1);
        o0[j] = oacc00[4 * rq + j] * inv0;
        o1[j] = oacc01[4 * rq + j] * inv0;
        o2[j] = oacc10[4 * rq + j] * inv1;
        o3[j] = oacc11[4 * rq + j] * inv1;
      }
      *(f32x4*)&outp[obase + (size_t)d0 * T_SEQ + tbase] = o0;
      *(f32x4*)&outp[obase + (size_t)d1 * T_SEQ + tbase] = o1;
      *(f32x4*)&outp[obase + (size_t)d0 * T_SEQ + tbase + 32] = o2;
      *(f32x4*)&outp[obase + (size_t)d1 * T_SEQ + tbase + 32] = o3;
    }
  }
}

extern "C" void kernel_launch(void* const* d_in, const int* in_sizes, int n_in,
                              void* d_out, int out_size, void* d_ws, size_t ws_size,
                              hipStream_t stream) {
  (void)in_sizes; (void)n_in; (void)out_size; (void)ws_size;
  const float* x  = (const float*)d_in[0];
  const float* Wq = (const float*)d_in[1];
  const float* Wk = (const float*)d_in[2];
  const float* Wv = (const float*)d_in[3];
  float* outp = (float*)d_out;

  char* ws = (char*)d_ws;
  unsigned short* wb = (unsigned short*)ws;                       // 786432 B
  unsigned short* xT = (unsigned short*)(ws + 786432);            // 4194304 B
  unsigned short* qb = (unsigned short*)(ws + 4980736);           // 8388608 B each
  unsigned short* kb = qb + 4194304;
  unsigned short* vb = kb + 4194304;                              // vb is d-major [nh][64][2048]

  pack_w_k<<<1536, 256, 0, stream>>>(Wq, Wk, Wv, wb);
  pack_xT_k<<<dim3(32, 4, 4), 256, 0, stream>>>(x, xT);
  proj_k<<<dim3(8, 16, 4), 256, 0, stream>>>(wb, xT, qb, kb, vb);
  attn_k<<<256, 512, 0, stream>>>(qb, kb, vb, outp);
}